// Round 1
// baseline (394.607 us; speedup 1.0000x reference)
//
#include <hip/hip_runtime.h>

#define T_TOK 4096
#define D_DIM 512
#define F_DIM 1024
#define E_NUM 8
#define CAP   4096
#define BM    128
#define BN    64
#define BK    64
#define MT    (CAP/BM)   // 32

typedef __bf16 bf16x8 __attribute__((ext_vector_type(8)));
typedef float  f32x4  __attribute__((ext_vector_type(4)));

__device__ __forceinline__ unsigned short f2bf(float f){
  unsigned int u = __builtin_bit_cast(unsigned int, f);
  u += 0x7FFFu + ((u >> 16) & 1u);
  return (unsigned short)(u >> 16);
}

__device__ __forceinline__ void gload16(const void* g, void* l){
  __builtin_amdgcn_global_load_lds(
      (const __attribute__((address_space(1))) unsigned int*)g,
      (__attribute__((address_space(3))) unsigned int*)l, 16, 0, 0);
}

// ---------------- pre-pass: fp32 -> bf16 convert ----------------
__global__ __launch_bounds__(256) void convert_x_kernel(
    const float* __restrict__ in, unsigned short* __restrict__ outb, int n4){
  int i = blockIdx.x*256 + threadIdx.x;
  if (i >= n4) return;
  float4 v = ((const float4*)in)[i];
  ushort4 o;
  o.x = f2bf(v.x); o.y = f2bf(v.y); o.z = f2bf(v.z); o.w = f2bf(v.w);
  ((ushort4*)outb)[i] = o;
}

// in [E][R][C] fp32 -> out [E][C][R] bf16
__global__ __launch_bounds__(256) void transpose_kernel(
    const float* __restrict__ in, unsigned short* __restrict__ outb, int R, int C){
  int e = blockIdx.z;
  int c0 = blockIdx.x*64, r0 = blockIdx.y*64;
  const float* src = in + (size_t)e*R*C;
  unsigned short* dst = outb + (size_t)e*R*C;
  __shared__ unsigned short tile[64][72];
  int tid = threadIdx.x;
  #pragma unroll
  for (int i=0;i<16;i++){
    int idx = i*256+tid; int rl = idx>>6, cl = idx&63;
    tile[cl][rl] = f2bf(src[(size_t)(r0+rl)*C + (c0+cl)]);
  }
  __syncthreads();
  #pragma unroll
  for (int i=0;i<16;i++){
    int idx = i*256+tid; int cl = idx>>6, rl = idx&63;
    dst[(size_t)(c0+cl)*R + (r0+rl)] = tile[cl][rl];
  }
}

// ---------------- router ----------------
__global__ __launch_bounds__(256) void router_kernel(
    const float* __restrict__ x, const float* __restrict__ rw,
    int* __restrict__ cnt, int* __restrict__ slot_token, float* __restrict__ slot_w,
    float* __restrict__ Psum, float* __restrict__ zsum){
  __shared__ float rws[E_NUM*D_DIM];
  __shared__ float pacc[E_NUM];
  __shared__ float zacc;
  int tid = threadIdx.x;
  if (tid < E_NUM) pacc[tid] = 0.f;
  if (tid == E_NUM) zacc = 0.f;
  for (int i = tid; i < E_NUM*D_DIM; i += 256) rws[i] = rw[i];
  __syncthreads();
  int wid = tid>>6, lane = tid&63;
  int t = blockIdx.x*4 + wid;
  const float* xr = x + (size_t)t*D_DIM + lane*8;
  float4 xa = *(const float4*)xr;
  float4 xb = *(const float4*)(xr+4);
  float logit[E_NUM];
  #pragma unroll
  for (int e=0;e<E_NUM;e++){
    const float* wr = rws + e*D_DIM + lane*8;
    float4 wa = *(const float4*)wr;
    float4 wb = *(const float4*)(wr+4);
    float s = xa.x*wa.x + xa.y*wa.y + xa.z*wa.z + xa.w*wa.w
            + xb.x*wb.x + xb.y*wb.y + xb.z*wb.z + xb.w*wb.w;
    #pragma unroll
    for (int m=1;m<64;m<<=1) s += __shfl_xor(s, m);
    logit[e] = s;
  }
  float mx = logit[0];
  #pragma unroll
  for (int e=1;e<E_NUM;e++) mx = fmaxf(mx, logit[e]);
  float p[E_NUM]; float s = 0.f;
  #pragma unroll
  for (int e=0;e<E_NUM;e++){ p[e] = expf(logit[e]-mx); s += p[e]; }
  float inv = 1.f/s;
  #pragma unroll
  for (int e=0;e<E_NUM;e++) p[e] *= inv;
  float lse = mx + logf(s);
  int i1 = 0;
  #pragma unroll
  for (int e=1;e<E_NUM;e++) if (logit[e] > logit[i1]) i1 = e;
  int i2 = (i1==0) ? 1 : 0;
  #pragma unroll
  for (int e=0;e<E_NUM;e++) if (e != i1 && logit[e] > logit[i2]) i2 = e;
  if (lane == 0){
    float v1 = p[i1], v2 = p[i2];
    float invw = 1.f/(v1+v2);
    int pos1 = atomicAdd(&cnt[i1], 1);
    slot_token[i1*CAP + pos1] = t;
    slot_w[i1*CAP + pos1] = v1*invw;
    int pos2 = atomicAdd(&cnt[i2], 1);
    slot_token[i2*CAP + pos2] = t;
    slot_w[i2*CAP + pos2] = v2*invw;
    #pragma unroll
    for (int e=0;e<E_NUM;e++) atomicAdd(&pacc[e], p[e]);
    atomicAdd(&zacc, lse*lse);
  }
  __syncthreads();
  if (tid < E_NUM) atomicAdd(&Psum[tid], pacc[tid]);
  if (tid == E_NUM) atomicAdd(zsum, zacc);
}

// ---------------- prefix offsets + aux loss ----------------
__global__ void finalize_kernel(const int* __restrict__ cnt, const float* __restrict__ Psum,
                                const float* __restrict__ zsum, int* __restrict__ off,
                                float* __restrict__ aux){
  if (threadIdx.x == 0 && blockIdx.x == 0){
    int o = 0; float lb = 0.f;
    #pragma unroll
    for (int e=0;e<E_NUM;e++){
      off[e] = o; o += cnt[e];
      float f = (float)cnt[e] / (float)(T_TOK*2);
      float P = Psum[e] / (float)T_TOK;
      lb += f*P;
    }
    float z = zsum[0] / (float)T_TOK;
    aux[0] = 0.01f * ((float)E_NUM * lb) + 0.001f * z;
  }
}

// ---------------- gate+up GEMM, silu fused, H written (bf16) ----------------
__global__ __launch_bounds__(256) void gemm_gateup(
    const unsigned short* __restrict__ xb, const unsigned short* __restrict__ gwt,
    const unsigned short* __restrict__ uwt,
    const int* __restrict__ cnt, const int* __restrict__ off,
    const int* __restrict__ slot_token, const float* __restrict__ slot_w,
    unsigned short* __restrict__ H, const unsigned short* __restrict__ zp)
{
  int e  = blockIdx.x >> 5;
  int mt = blockIdx.x & 31;
  int c = cnt[e];
  int row0 = mt*BM;
  if (row0 >= c) return;
  int rem = c - row0;
  int n0 = blockIdx.y * BN;
  int tid = threadIdx.x, wid = tid>>6, lane = tid&63;
  __shared__ unsigned short lds[BM*BK + 2*BN*BK];
  unsigned short* As = lds;
  unsigned short* Bg = lds + BM*BK;
  unsigned short* Bu = Bg + BN*BK;

  int sub = lane>>3;
  int skb = ((lane&7)<<4) ^ (sub<<4);
  const char* asrc[4];
  #pragma unroll
  for (int i=0;i<4;i++){
    int r = (wid*4+i)*8 + sub;
    int tok = (r < rem) ? slot_token[e*CAP + row0 + r] : -1;
    asrc[i] = (tok >= 0) ? ((const char*)xb + (size_t)tok*(D_DIM*2) + skb)
                         : ((const char*)zp + skb);
  }
  const char* bgsrc[2]; const char* busrc[2];
  #pragma unroll
  for (int i=0;i<2;i++){
    int r = (wid*2+i)*8 + sub;
    size_t rowb = ((size_t)e*F_DIM + n0 + r) * (D_DIM*2);
    bgsrc[i] = (const char*)gwt + rowb + skb;
    busrc[i] = (const char*)uwt + rowb + skb;
  }

  f32x4 accg[4][2] = {};
  f32x4 accu[4][2] = {};
  int wm = wid>>1, wn = wid&1;

  size_t koff = 0;
  for (int kt=0; kt<D_DIM/BK; ++kt, koff += BK*2){
    #pragma unroll
    for (int i=0;i<4;i++)
      gload16(asrc[i]+koff, (char*)As + (wid*4+i)*1024);
    #pragma unroll
    for (int i=0;i<2;i++){
      gload16(bgsrc[i]+koff, (char*)Bg + (wid*2+i)*1024);
      gload16(busrc[i]+koff, (char*)Bu + (wid*2+i)*1024);
    }
    __syncthreads();
    #pragma unroll
    for (int s=0;s<2;s++){
      int kc = s*4 + (lane>>4);
      bf16x8 a[4], bg[2], bu[2];
      #pragma unroll
      for (int m=0;m<4;m++){
        int ar = wm*64 + m*16 + (lane&15);
        a[m] = *(const bf16x8*)((const char*)As + ar*128 + ((kc<<4) ^ ((ar&7)<<4)));
      }
      #pragma unroll
      for (int n=0;n<2;n++){
        int br = wn*32 + n*16 + (lane&15);
        int bo = br*128 + ((kc<<4) ^ ((br&7)<<4));
        bg[n] = *(const bf16x8*)((const char*)Bg + bo);
        bu[n] = *(const bf16x8*)((const char*)Bu + bo);
      }
      #pragma unroll
      for (int m=0;m<4;m++){
        #pragma unroll
        for (int n=0;n<2;n++){
          accg[m][n] = __builtin_amdgcn_mfma_f32_16x16x32_bf16(a[m], bg[n], accg[m][n], 0,0,0);
          accu[m][n] = __builtin_amdgcn_mfma_f32_16x16x32_bf16(a[m], bu[n], accu[m][n], 0,0,0);
        }
      }
    }
    __syncthreads();
  }

  int offe = off[e];
  #pragma unroll
  for (int m=0;m<4;m++){
    #pragma unroll
    for (int j=0;j<4;j++){
      int row = wm*64 + m*16 + ((lane>>4)<<2) + j;
      if (row < rem){
        float wgt = slot_w[e*CAP + row0 + row];
        size_t hb = (size_t)(offe + row0 + row)*F_DIM;
        #pragma unroll
        for (int n=0;n<2;n++){
          int col = n0 + wn*32 + n*16 + (lane&15);
          float g = accg[m][n][j];
          float u = accu[m][n][j];
          float h = g * (1.f/(1.f+__expf(-g))) * u * wgt;
          H[hb + col] = f2bf(h);
        }
      }
    }
  }
}

// ---------------- down GEMM, atomic scatter into out ----------------
__global__ __launch_bounds__(256) void gemm_down(
    const unsigned short* __restrict__ H, const unsigned short* __restrict__ dwt,
    const int* __restrict__ cnt, const int* __restrict__ off,
    const int* __restrict__ slot_token,
    float* __restrict__ out, const unsigned short* __restrict__ zp)
{
  int e = blockIdx.x >> 5, mt = blockIdx.x & 31;
  int c = cnt[e]; int row0 = mt*BM;
  if (row0 >= c) return;
  int rem = c - row0;
  int n0 = blockIdx.y * BN;
  int tid = threadIdx.x, wid = tid>>6, lane = tid&63;
  __shared__ unsigned short lds[BM*BK + BN*BK];
  unsigned short* As = lds;
  unsigned short* Bs = lds + BM*BK;
  int sub = lane>>3;
  int skb = ((lane&7)<<4) ^ (sub<<4);
  int offe = off[e];
  const char* asrc[4];
  #pragma unroll
  for (int i=0;i<4;i++){
    int r = (wid*4+i)*8 + sub;
    asrc[i] = (r < rem) ? ((const char*)H + (size_t)(offe+row0+r)*(F_DIM*2) + skb)
                        : ((const char*)zp + skb);
  }
  const char* bsrc[2];
  #pragma unroll
  for (int i=0;i<2;i++){
    int r = (wid*2+i)*8 + sub;
    bsrc[i] = (const char*)dwt + ((size_t)e*D_DIM + n0 + r)*(F_DIM*2) + skb;
  }
  f32x4 acc[4][2] = {};
  int wm = wid>>1, wn = wid&1;
  size_t koff = 0;
  for (int kt=0; kt<F_DIM/BK; ++kt, koff += BK*2){
    #pragma unroll
    for (int i=0;i<4;i++) gload16(asrc[i]+koff, (char*)As + (wid*4+i)*1024);
    #pragma unroll
    for (int i=0;i<2;i++) gload16(bsrc[i]+koff, (char*)Bs + (wid*2+i)*1024);
    __syncthreads();
    #pragma unroll
    for (int s=0;s<2;s++){
      int kc = s*4 + (lane>>4);
      bf16x8 a[4], b[2];
      #pragma unroll
      for (int m=0;m<4;m++){
        int ar = wm*64 + m*16 + (lane&15);
        a[m] = *(const bf16x8*)((const char*)As + ar*128 + ((kc<<4) ^ ((ar&7)<<4)));
      }
      #pragma unroll
      for (int n=0;n<2;n++){
        int br = wn*32 + n*16 + (lane&15);
        b[n] = *(const bf16x8*)((const char*)Bs + br*128 + ((kc<<4) ^ ((br&7)<<4)));
      }
      #pragma unroll
      for (int m=0;m<4;m++){
        #pragma unroll
        for (int n=0;n<2;n++)
          acc[m][n] = __builtin_amdgcn_mfma_f32_16x16x32_bf16(a[m], b[n], acc[m][n], 0,0,0);
      }
    }
    __syncthreads();
  }
  #pragma unroll
  for (int m=0;m<4;m++){
    #pragma unroll
    for (int j=0;j<4;j++){
      int row = wm*64 + m*16 + ((lane>>4)<<2) + j;
      if (row < rem){
        int tok = slot_token[e*CAP + row0 + row];
        #pragma unroll
        for (int n=0;n<2;n++){
          int col = n0 + wn*32 + n*16 + (lane&15);
          atomicAdd(&out[(size_t)tok*D_DIM + col], acc[m][n][j]);
        }
      }
    }
  }
}

extern "C" void kernel_launch(void* const* d_in, const int* in_sizes, int n_in,
                              void* d_out, int out_size, void* d_ws, size_t ws_size,
                              hipStream_t stream){
  const float* x  = (const float*)d_in[0];
  const float* rw = (const float*)d_in[1];
  const float* gw = (const float*)d_in[2];
  const float* uw = (const float*)d_in[3];
  const float* dw = (const float*)d_in[4];
  float* out = (float*)d_out;

  char* w = (char*)d_ws;
  unsigned short* xb  = (unsigned short*)w;  w += (size_t)T_TOK*D_DIM*2;
  unsigned short* gwt = (unsigned short*)w;  w += (size_t)E_NUM*D_DIM*F_DIM*2;
  unsigned short* uwt = (unsigned short*)w;  w += (size_t)E_NUM*D_DIM*F_DIM*2;
  unsigned short* dwt = (unsigned short*)w;  w += (size_t)E_NUM*F_DIM*D_DIM*2;
  unsigned short* H   = (unsigned short*)w;  w += (size_t)(T_TOK*2)*F_DIM*2;
  int*   slot_token = (int*)w;               w += (size_t)E_NUM*CAP*4;
  float* slot_w     = (float*)w;             w += (size_t)E_NUM*CAP*4;
  char* meta = w;
  int*   cnt  = (int*)w;       w += 32;
  int*   off  = (int*)w;       w += 32;
  float* Psum = (float*)w;     w += 32;
  float* zsum = (float*)w;     w += 32;
  w = (char*)(((uintptr_t)w + 255) & ~(uintptr_t)255);
  unsigned short* zp = (unsigned short*)w;   w += 4096;
  size_t meta_bytes = (size_t)(w - meta);

  hipMemsetAsync(d_out, 0, (size_t)out_size*sizeof(float), stream);
  hipMemsetAsync(meta, 0, meta_bytes, stream);

  convert_x_kernel<<<(T_TOK*D_DIM/4+255)/256, 256, 0, stream>>>(x, xb, T_TOK*D_DIM/4);
  transpose_kernel<<<dim3(F_DIM/64, D_DIM/64, E_NUM), 256, 0, stream>>>(gw, gwt, D_DIM, F_DIM);
  transpose_kernel<<<dim3(F_DIM/64, D_DIM/64, E_NUM), 256, 0, stream>>>(uw, uwt, D_DIM, F_DIM);
  transpose_kernel<<<dim3(D_DIM/64, F_DIM/64, E_NUM), 256, 0, stream>>>(dw, dwt, F_DIM, D_DIM);
  router_kernel<<<T_TOK/4, 256, 0, stream>>>(x, rw, cnt, slot_token, slot_w, Psum, zsum);
  finalize_kernel<<<1, 64, 0, stream>>>(cnt, Psum, zsum, off, out + (size_t)T_TOK*D_DIM);
  gemm_gateup<<<dim3(E_NUM*MT, F_DIM/BN), 256, 0, stream>>>(xb, gwt, uwt, cnt, off, slot_token, slot_w, H, zp);
  gemm_down<<<dim3(E_NUM*MT, D_DIM/BN), 256, 0, stream>>>(H, dwt, cnt, off, slot_token, out, zp);
}

// Round 2
// 307.400 us; speedup vs baseline: 1.2837x; 1.2837x over previous
//
#include <hip/hip_runtime.h>

#define T_TOK 4096
#define D_DIM 512
#define F_DIM 1024
#define E_NUM 8
#define CAP   4096
#define BM    128
#define BN    64
#define BK    64
#define MT    (CAP/BM)   // 32
#define RB_TOK 32        // tokens per router block
#define CSTRIDE 32       // cacheline padding for counters (ints/floats)

typedef __bf16 bf16x8 __attribute__((ext_vector_type(8)));
typedef float  f32x4  __attribute__((ext_vector_type(4)));

__device__ __forceinline__ unsigned short f2bf(float f){
  unsigned int u = __builtin_bit_cast(unsigned int, f);
  u += 0x7FFFu + ((u >> 16) & 1u);
  return (unsigned short)(u >> 16);
}

__device__ __forceinline__ void gload16(const void* g, void* l){
  __builtin_amdgcn_global_load_lds(
      (const __attribute__((address_space(1))) unsigned int*)g,
      (__attribute__((address_space(3))) unsigned int*)l, 16, 0, 0);
}

// in [E][R][C] fp32 -> out [E][C][R] bf16
__global__ __launch_bounds__(256) void transpose_kernel(
    const float* __restrict__ in, unsigned short* __restrict__ outb, int R, int C){
  int e = blockIdx.z;
  int c0 = blockIdx.x*64, r0 = blockIdx.y*64;
  const float* src = in + (size_t)e*R*C;
  unsigned short* dst = outb + (size_t)e*R*C;
  __shared__ unsigned short tile[64][72];
  int tid = threadIdx.x;
  #pragma unroll
  for (int i=0;i<16;i++){
    int idx = i*256+tid; int rl = idx>>6, cl = idx&63;
    tile[cl][rl] = f2bf(src[(size_t)(r0+rl)*C + (c0+cl)]);
  }
  __syncthreads();
  #pragma unroll
  for (int i=0;i<16;i++){
    int idx = i*256+tid; int cl = idx>>6, rl = idx&63;
    dst[(size_t)(c0+cl)*R + (r0+rl)] = tile[cl][rl];
  }
}

// ---------------- router v2: block-aggregated atomics + fused x->bf16 ----------------
__global__ __launch_bounds__(256) void router_kernel(
    const float* __restrict__ x, const float* __restrict__ rw,
    unsigned short* __restrict__ xb,
    int* __restrict__ cnt, int* __restrict__ slot_token, float* __restrict__ slot_w,
    float* __restrict__ Psum, float* __restrict__ zsum){
  __shared__ float rws[E_NUM*D_DIM];
  __shared__ float lp[RB_TOK][E_NUM];
  __shared__ float lw1[RB_TOK], lw2[RB_TOK], llse[RB_TOK];
  __shared__ int   li1[RB_TOK], li2[RB_TOK];
  int tid = threadIdx.x, wid = tid>>6, lane = tid&63;
  for (int i = tid; i < E_NUM*D_DIM; i += 256) rws[i] = rw[i];
  __syncthreads();

  #pragma unroll
  for (int i=0;i<8;i++){
    int widx = wid*8 + i;
    int t = blockIdx.x*RB_TOK + widx;
    const float* xr = x + (size_t)t*D_DIM + lane*8;
    float4 xa = *(const float4*)xr;
    float4 xc = *(const float4*)(xr+4);
    // fused fp32->bf16 write of x
    uint4 pk;
    pk.x = (unsigned)f2bf(xa.x) | ((unsigned)f2bf(xa.y)<<16);
    pk.y = (unsigned)f2bf(xa.z) | ((unsigned)f2bf(xa.w)<<16);
    pk.z = (unsigned)f2bf(xc.x) | ((unsigned)f2bf(xc.y)<<16);
    pk.w = (unsigned)f2bf(xc.z) | ((unsigned)f2bf(xc.w)<<16);
    *(uint4*)(xb + (size_t)t*D_DIM + lane*8) = pk;

    float logit[E_NUM];
    #pragma unroll
    for (int e=0;e<E_NUM;e++){
      const float* wr = rws + e*D_DIM + lane*8;
      float4 wa = *(const float4*)wr;
      float4 wb = *(const float4*)(wr+4);
      float s = xa.x*wa.x + xa.y*wa.y + xa.z*wa.z + xa.w*wa.w
              + xc.x*wb.x + xc.y*wb.y + xc.z*wb.z + xc.w*wb.w;
      #pragma unroll
      for (int m=1;m<64;m<<=1) s += __shfl_xor(s, m);
      logit[e] = s;
    }
    float mx = logit[0];
    #pragma unroll
    for (int e=1;e<E_NUM;e++) mx = fmaxf(mx, logit[e]);
    float p[E_NUM]; float s = 0.f;
    #pragma unroll
    for (int e=0;e<E_NUM;e++){ p[e] = __expf(logit[e]-mx); s += p[e]; }
    float inv = 1.f/s;
    #pragma unroll
    for (int e=0;e<E_NUM;e++) p[e] *= inv;
    float lse = mx + __logf(s);
    int i1 = 0;
    #pragma unroll
    for (int e=1;e<E_NUM;e++) if (logit[e] > logit[i1]) i1 = e;
    int i2 = (i1==0) ? 1 : 0;
    #pragma unroll
    for (int e=0;e<E_NUM;e++) if (e != i1 && logit[e] > logit[i2]) i2 = e;
    if (lane == 0){
      float v1 = p[i1], v2 = p[i2];
      float invw = 1.f/(v1+v2);
      li1[widx] = i1; li2[widx] = i2;
      lw1[widx] = v1*invw; lw2[widx] = v2*invw;
      llse[widx] = lse;
      #pragma unroll
      for (int e=0;e<E_NUM;e++) lp[widx][e] = p[e];
    }
  }
  __syncthreads();

  if (tid < E_NUM){
    int e = tid, c = 0;
    #pragma unroll 4
    for (int j=0;j<RB_TOK;j++) c += (li1[j]==e) + (li2[j]==e);
    int idx = atomicAdd(&cnt[e*CSTRIDE], c);
    int tbase = blockIdx.x*RB_TOK;
    for (int j=0;j<RB_TOK;j++){
      if (li1[j]==e){ slot_token[e*CAP+idx] = tbase+j; slot_w[e*CAP+idx] = lw1[j]; idx++; }
      if (li2[j]==e){ slot_token[e*CAP+idx] = tbase+j; slot_w[e*CAP+idx] = lw2[j]; idx++; }
    }
    float ps = 0.f;
    #pragma unroll 4
    for (int j=0;j<RB_TOK;j++) ps += lp[j][e];
    atomicAdd(&Psum[e*CSTRIDE], ps);
  } else if (tid == 64){
    float zs = 0.f;
    #pragma unroll 4
    for (int j=0;j<RB_TOK;j++){ float l = llse[j]; zs += l*l; }
    atomicAdd(zsum, zs);
  }
}

// ---------------- prefix offsets + aux loss ----------------
__global__ void finalize_kernel(const int* __restrict__ cnt, const float* __restrict__ Psum,
                                const float* __restrict__ zsum, int* __restrict__ off,
                                float* __restrict__ aux){
  if (threadIdx.x == 0 && blockIdx.x == 0){
    int o = 0; float lb = 0.f;
    #pragma unroll
    for (int e=0;e<E_NUM;e++){
      off[e] = o; o += cnt[e*CSTRIDE];
      float f = (float)cnt[e*CSTRIDE] / (float)(T_TOK*2);
      float P = Psum[e*CSTRIDE] / (float)T_TOK;
      lb += f*P;
    }
    float z = zsum[0] / (float)T_TOK;
    aux[0] = 0.01f * ((float)E_NUM * lb) + 0.001f * z;
  }
}

// ---------------- gate+up GEMM, silu fused, H written (bf16) ----------------
__global__ __launch_bounds__(256) void gemm_gateup(
    const unsigned short* __restrict__ xb, const unsigned short* __restrict__ gwt,
    const unsigned short* __restrict__ uwt,
    const int* __restrict__ cnt, const int* __restrict__ off,
    const int* __restrict__ slot_token, const float* __restrict__ slot_w,
    unsigned short* __restrict__ H, const unsigned short* __restrict__ zp)
{
  int e  = blockIdx.x >> 5;
  int mt = blockIdx.x & 31;
  int c = cnt[e*CSTRIDE];
  int row0 = mt*BM;
  if (row0 >= c) return;
  int rem = c - row0;
  int n0 = blockIdx.y * BN;
  int tid = threadIdx.x, wid = tid>>6, lane = tid&63;
  __shared__ unsigned short lds[BM*BK + 2*BN*BK];
  unsigned short* As = lds;
  unsigned short* Bg = lds + BM*BK;
  unsigned short* Bu = Bg + BN*BK;

  int sub = lane>>3;
  int skb = ((lane&7)<<4) ^ (sub<<4);
  const char* asrc[4];
  #pragma unroll
  for (int i=0;i<4;i++){
    int r = (wid*4+i)*8 + sub;
    int tok = (r < rem) ? slot_token[e*CAP + row0 + r] : -1;
    asrc[i] = (tok >= 0) ? ((const char*)xb + (size_t)tok*(D_DIM*2) + skb)
                         : ((const char*)zp + skb);
  }
  const char* bgsrc[2]; const char* busrc[2];
  #pragma unroll
  for (int i=0;i<2;i++){
    int r = (wid*2+i)*8 + sub;
    size_t rowb = ((size_t)e*F_DIM + n0 + r) * (D_DIM*2);
    bgsrc[i] = (const char*)gwt + rowb + skb;
    busrc[i] = (const char*)uwt + rowb + skb;
  }

  f32x4 accg[4][2] = {};
  f32x4 accu[4][2] = {};
  int wm = wid>>1, wn = wid&1;

  size_t koff = 0;
  for (int kt=0; kt<D_DIM/BK; ++kt, koff += BK*2){
    #pragma unroll
    for (int i=0;i<4;i++)
      gload16(asrc[i]+koff, (char*)As + (wid*4+i)*1024);
    #pragma unroll
    for (int i=0;i<2;i++){
      gload16(bgsrc[i]+koff, (char*)Bg + (wid*2+i)*1024);
      gload16(busrc[i]+koff, (char*)Bu + (wid*2+i)*1024);
    }
    __syncthreads();
    #pragma unroll
    for (int s=0;s<2;s++){
      int kc = s*4 + (lane>>4);
      bf16x8 a[4], bg[2], bu[2];
      #pragma unroll
      for (int m=0;m<4;m++){
        int ar = wm*64 + m*16 + (lane&15);
        a[m] = *(const bf16x8*)((const char*)As + ar*128 + ((kc<<4) ^ ((ar&7)<<4)));
      }
      #pragma unroll
      for (int n=0;n<2;n++){
        int br = wn*32 + n*16 + (lane&15);
        int bo = br*128 + ((kc<<4) ^ ((br&7)<<4));
        bg[n] = *(const bf16x8*)((const char*)Bg + bo);
        bu[n] = *(const bf16x8*)((const char*)Bu + bo);
      }
      #pragma unroll
      for (int m=0;m<4;m++){
        #pragma unroll
        for (int n=0;n<2;n++){
          accg[m][n] = __builtin_amdgcn_mfma_f32_16x16x32_bf16(a[m], bg[n], accg[m][n], 0,0,0);
          accu[m][n] = __builtin_amdgcn_mfma_f32_16x16x32_bf16(a[m], bu[n], accu[m][n], 0,0,0);
        }
      }
    }
    __syncthreads();
  }

  int offe = off[e];
  #pragma unroll
  for (int m=0;m<4;m++){
    #pragma unroll
    for (int j=0;j<4;j++){
      int row = wm*64 + m*16 + ((lane>>4)<<2) + j;
      if (row < rem){
        float wgt = slot_w[e*CAP + row0 + row];
        size_t hb = (size_t)(offe + row0 + row)*F_DIM;
        #pragma unroll
        for (int n=0;n<2;n++){
          int col = n0 + wn*32 + n*16 + (lane&15);
          float g = accg[m][n][j];
          float u = accu[m][n][j];
          float h = g * (1.f/(1.f+__expf(-g))) * u * wgt;
          H[hb + col] = f2bf(h);
        }
      }
    }
  }
}

// ---------------- down GEMM, atomic scatter into out ----------------
__global__ __launch_bounds__(256) void gemm_down(
    const unsigned short* __restrict__ H, const unsigned short* __restrict__ dwt,
    const int* __restrict__ cnt, const int* __restrict__ off,
    const int* __restrict__ slot_token,
    float* __restrict__ out, const unsigned short* __restrict__ zp)
{
  int e = blockIdx.x >> 5, mt = blockIdx.x & 31;
  int c = cnt[e*CSTRIDE]; int row0 = mt*BM;
  if (row0 >= c) return;
  int rem = c - row0;
  int n0 = blockIdx.y * BN;
  int tid = threadIdx.x, wid = tid>>6, lane = tid&63;
  __shared__ unsigned short lds[BM*BK + BN*BK];
  unsigned short* As = lds;
  unsigned short* Bs = lds + BM*BK;
  int sub = lane>>3;
  int skb = ((lane&7)<<4) ^ (sub<<4);
  int offe = off[e];
  const char* asrc[4];
  #pragma unroll
  for (int i=0;i<4;i++){
    int r = (wid*4+i)*8 + sub;
    asrc[i] = (r < rem) ? ((const char*)H + (size_t)(offe+row0+r)*(F_DIM*2) + skb)
                        : ((const char*)zp + skb);
  }
  const char* bsrc[2];
  #pragma unroll
  for (int i=0;i<2;i++){
    int r = (wid*2+i)*8 + sub;
    bsrc[i] = (const char*)dwt + ((size_t)e*D_DIM + n0 + r)*(F_DIM*2) + skb;
  }
  f32x4 acc[4][2] = {};
  int wm = wid>>1, wn = wid&1;
  size_t koff = 0;
  for (int kt=0; kt<F_DIM/BK; ++kt, koff += BK*2){
    #pragma unroll
    for (int i=0;i<4;i++) gload16(asrc[i]+koff, (char*)As + (wid*4+i)*1024);
    #pragma unroll
    for (int i=0;i<2;i++) gload16(bsrc[i]+koff, (char*)Bs + (wid*2+i)*1024);
    __syncthreads();
    #pragma unroll
    for (int s=0;s<2;s++){
      int kc = s*4 + (lane>>4);
      bf16x8 a[4], b[2];
      #pragma unroll
      for (int m=0;m<4;m++){
        int ar = wm*64 + m*16 + (lane&15);
        a[m] = *(const bf16x8*)((const char*)As + ar*128 + ((kc<<4) ^ ((ar&7)<<4)));
      }
      #pragma unroll
      for (int n=0;n<2;n++){
        int br = wn*32 + n*16 + (lane&15);
        b[n] = *(const bf16x8*)((const char*)Bs + br*128 + ((kc<<4) ^ ((br&7)<<4)));
      }
      #pragma unroll
      for (int m=0;m<4;m++){
        #pragma unroll
        for (int n=0;n<2;n++)
          acc[m][n] = __builtin_amdgcn_mfma_f32_16x16x32_bf16(a[m], b[n], acc[m][n], 0,0,0);
      }
    }
    __syncthreads();
  }
  #pragma unroll
  for (int m=0;m<4;m++){
    #pragma unroll
    for (int j=0;j<4;j++){
      int row = wm*64 + m*16 + ((lane>>4)<<2) + j;
      if (row < rem){
        int tok = slot_token[e*CAP + row0 + row];
        #pragma unroll
        for (int n=0;n<2;n++){
          int col = n0 + wn*32 + n*16 + (lane&15);
          atomicAdd(&out[(size_t)tok*D_DIM + col], acc[m][n][j]);
        }
      }
    }
  }
}

extern "C" void kernel_launch(void* const* d_in, const int* in_sizes, int n_in,
                              void* d_out, int out_size, void* d_ws, size_t ws_size,
                              hipStream_t stream){
  const float* x  = (const float*)d_in[0];
  const float* rw = (const float*)d_in[1];
  const float* gw = (const float*)d_in[2];
  const float* uw = (const float*)d_in[3];
  const float* dw = (const float*)d_in[4];
  float* out = (float*)d_out;

  char* w = (char*)d_ws;
  unsigned short* xb  = (unsigned short*)w;  w += (size_t)T_TOK*D_DIM*2;
  unsigned short* gwt = (unsigned short*)w;  w += (size_t)E_NUM*D_DIM*F_DIM*2;
  unsigned short* uwt = (unsigned short*)w;  w += (size_t)E_NUM*D_DIM*F_DIM*2;
  unsigned short* dwt = (unsigned short*)w;  w += (size_t)E_NUM*F_DIM*D_DIM*2;
  unsigned short* H   = (unsigned short*)w;  w += (size_t)(T_TOK*2)*F_DIM*2;
  int*   slot_token = (int*)w;               w += (size_t)E_NUM*CAP*4;
  float* slot_w     = (float*)w;             w += (size_t)E_NUM*CAP*4;
  char* meta = w;
  int*   cnt  = (int*)w;       w += E_NUM*CSTRIDE*4;
  int*   off  = (int*)w;       w += 128;
  float* Psum = (float*)w;     w += E_NUM*CSTRIDE*4;
  float* zsum = (float*)w;     w += 128;
  w = (char*)(((uintptr_t)w + 255) & ~(uintptr_t)255);
  unsigned short* zp = (unsigned short*)w;   w += 4096;
  size_t meta_bytes = (size_t)(w - meta);

  hipMemsetAsync(d_out, 0, (size_t)out_size*sizeof(float), stream);
  hipMemsetAsync(meta, 0, meta_bytes, stream);

  transpose_kernel<<<dim3(F_DIM/64, D_DIM/64, E_NUM), 256, 0, stream>>>(gw, gwt, D_DIM, F_DIM);
  transpose_kernel<<<dim3(F_DIM/64, D_DIM/64, E_NUM), 256, 0, stream>>>(uw, uwt, D_DIM, F_DIM);
  transpose_kernel<<<dim3(D_DIM/64, F_DIM/64, E_NUM), 256, 0, stream>>>(dw, dwt, F_DIM, D_DIM);
  router_kernel<<<T_TOK/RB_TOK, 256, 0, stream>>>(x, rw, xb, cnt, slot_token, slot_w, Psum, zsum);
  finalize_kernel<<<1, 64, 0, stream>>>(cnt, Psum, zsum, off, out + (size_t)T_TOK*D_DIM);
  gemm_gateup<<<dim3(E_NUM*MT, F_DIM/BN), 256, 0, stream>>>(xb, gwt, uwt, cnt, off, slot_token, slot_w, H, zp);
  gemm_down<<<dim3(E_NUM*MT, D_DIM/BN), 256, 0, stream>>>(H, dwt, cnt, off, slot_token, out, zp);
}

// Round 3
// 221.422 us; speedup vs baseline: 1.7822x; 1.3883x over previous
//
#include <hip/hip_runtime.h>

#define T_TOK 4096
#define D_DIM 512
#define F_DIM 1024
#define E_NUM 8
#define CAP   2048
#define BM    128
#define BN    64
#define BK    64
#define MT    (CAP/BM)      // 16
#define NT_GU (F_DIM/BN)    // 16
#define NT_DN (D_DIM/BN)    // 8
#define RB_TOK 32
#define CSTRIDE 32

typedef __bf16 bf16x8 __attribute__((ext_vector_type(8)));
typedef float  f32x4  __attribute__((ext_vector_type(4)));

__device__ __forceinline__ unsigned short f2bf(float f){
  unsigned int u = __builtin_bit_cast(unsigned int, f);
  u += 0x7FFFu + ((u >> 16) & 1u);
  return (unsigned short)(u >> 16);
}

__device__ __forceinline__ void gload16(const void* g, void* l){
  __builtin_amdgcn_global_load_lds(
      (const __attribute__((address_space(1))) unsigned int*)g,
      (__attribute__((address_space(3))) unsigned int*)l, 16, 0, 0);
}

// in [E][R][C] fp32 -> out [E][C][R] bf16
__global__ __launch_bounds__(256) void transpose_kernel(
    const float* __restrict__ in, unsigned short* __restrict__ outb, int R, int C){
  int e = blockIdx.z;
  int c0 = blockIdx.x*64, r0 = blockIdx.y*64;
  const float* src = in + (size_t)e*R*C;
  unsigned short* dst = outb + (size_t)e*R*C;
  __shared__ unsigned short tile[64][66];
  int tid = threadIdx.x;
  #pragma unroll
  for (int i=0;i<16;i++){
    int idx = i*256+tid; int rl = idx>>6, cl = idx&63;
    tile[cl][rl] = f2bf(src[(size_t)(r0+rl)*C + (c0+cl)]);
  }
  __syncthreads();
  #pragma unroll
  for (int i=0;i<16;i++){
    int idx = i*256+tid; int cl = idx>>6, rl = idx&63;
    dst[(size_t)(c0+cl)*R + (r0+rl)] = tile[cl][rl];
  }
}

// ---------------- router v3: logits + top2 + direct bf16 scatter into Xg ----------------
__global__ __launch_bounds__(256) void router_kernel(
    const float* __restrict__ x, const float* __restrict__ rw,
    unsigned short* __restrict__ Xg,
    int* __restrict__ cnt, int* __restrict__ slot_token, float* __restrict__ slot_w,
    float* __restrict__ Psum, float* __restrict__ zsum){
  __shared__ float rws[E_NUM*D_DIM];
  __shared__ float lp[RB_TOK][E_NUM];
  __shared__ float lw1[RB_TOK], lw2[RB_TOK], llse[RB_TOK];
  __shared__ int   li1[RB_TOK], li2[RB_TOK];
  __shared__ int   lsl1[RB_TOK], lsl2[RB_TOK];
  int tid = threadIdx.x, wid = tid>>6, lane = tid&63;
  for (int i = tid; i < E_NUM*D_DIM; i += 256) rws[i] = rw[i];
  __syncthreads();

  uint4 pk[8];
  #pragma unroll
  for (int i=0;i<8;i++){
    int widx = wid*8 + i;
    int t = blockIdx.x*RB_TOK + widx;
    const float* xr = x + (size_t)t*D_DIM + lane*8;
    float4 xa = *(const float4*)xr;
    float4 xc = *(const float4*)(xr+4);
    pk[i].x = (unsigned)f2bf(xa.x) | ((unsigned)f2bf(xa.y)<<16);
    pk[i].y = (unsigned)f2bf(xa.z) | ((unsigned)f2bf(xa.w)<<16);
    pk[i].z = (unsigned)f2bf(xc.x) | ((unsigned)f2bf(xc.y)<<16);
    pk[i].w = (unsigned)f2bf(xc.z) | ((unsigned)f2bf(xc.w)<<16);

    float logit[E_NUM];
    #pragma unroll
    for (int e=0;e<E_NUM;e++){
      const float* wr = rws + e*D_DIM + lane*8;
      float4 wa = *(const float4*)wr;
      float4 wb = *(const float4*)(wr+4);
      float s = xa.x*wa.x + xa.y*wa.y + xa.z*wa.z + xa.w*wa.w
              + xc.x*wb.x + xc.y*wb.y + xc.z*wb.z + xc.w*wb.w;
      #pragma unroll
      for (int m=1;m<64;m<<=1) s += __shfl_xor(s, m);
      logit[e] = s;
    }
    float mx = logit[0];
    #pragma unroll
    for (int e=1;e<E_NUM;e++) mx = fmaxf(mx, logit[e]);
    float p[E_NUM]; float s = 0.f;
    #pragma unroll
    for (int e=0;e<E_NUM;e++){ p[e] = __expf(logit[e]-mx); s += p[e]; }
    float inv = 1.f/s;
    #pragma unroll
    for (int e=0;e<E_NUM;e++) p[e] *= inv;
    float lse = mx + __logf(s);
    int i1 = 0;
    #pragma unroll
    for (int e=1;e<E_NUM;e++) if (logit[e] > logit[i1]) i1 = e;
    int i2 = (i1==0) ? 1 : 0;
    #pragma unroll
    for (int e=0;e<E_NUM;e++) if (e != i1 && logit[e] > logit[i2]) i2 = e;
    if (lane == 0){
      float v1 = p[i1], v2 = p[i2];
      float invw = 1.f/(v1+v2);
      li1[widx] = i1; li2[widx] = i2;
      lw1[widx] = v1*invw; lw2[widx] = v2*invw;
      llse[widx] = lse;
      #pragma unroll
      for (int e=0;e<E_NUM;e++) lp[widx][e] = p[e];
    }
  }
  __syncthreads();

  if (tid < E_NUM){
    int e = tid, c = 0;
    #pragma unroll 4
    for (int j=0;j<RB_TOK;j++) c += (li1[j]==e) + (li2[j]==e);
    int idx = atomicAdd(&cnt[e*CSTRIDE], c);
    int tbase = blockIdx.x*RB_TOK;
    for (int j=0;j<RB_TOK;j++){
      if (li1[j]==e){ slot_token[e*CAP+idx] = tbase+j; slot_w[e*CAP+idx] = lw1[j]; lsl1[j] = e*CAP+idx; idx++; }
      if (li2[j]==e){ slot_token[e*CAP+idx] = tbase+j; slot_w[e*CAP+idx] = lw2[j]; lsl2[j] = e*CAP+idx; idx++; }
    }
    float ps = 0.f;
    #pragma unroll 4
    for (int j=0;j<RB_TOK;j++) ps += lp[j][e];
    atomicAdd(&Psum[e*CSTRIDE], ps);
  } else if (tid == 64){
    float zs = 0.f;
    #pragma unroll 4
    for (int j=0;j<RB_TOK;j++){ float l = llse[j]; zs += l*l; }
    atomicAdd(zsum, zs);
  }
  __syncthreads();

  // scatter bf16 rows into per-expert slot matrix (2 destinations per token)
  #pragma unroll
  for (int i=0;i<8;i++){
    int widx = wid*8 + i;
    int s1 = lsl1[widx], s2 = lsl2[widx];
    *(uint4*)((char*)Xg + (size_t)s1*(D_DIM*2) + lane*16) = pk[i];
    *(uint4*)((char*)Xg + (size_t)s2*(D_DIM*2) + lane*16) = pk[i];
  }
}

// ---------------- prefix offsets + aux loss ----------------
__global__ void finalize_kernel(const int* __restrict__ cnt, const float* __restrict__ Psum,
                                const float* __restrict__ zsum, int* __restrict__ off,
                                float* __restrict__ aux){
  if (threadIdx.x == 0 && blockIdx.x == 0){
    int o = 0; float lb = 0.f;
    #pragma unroll
    for (int e=0;e<E_NUM;e++){
      off[e] = o; o += cnt[e*CSTRIDE];
      float f = (float)cnt[e*CSTRIDE] / (float)(T_TOK*2);
      float P = Psum[e*CSTRIDE] / (float)T_TOK;
      lb += f*P;
    }
    float z = zsum[0] / (float)T_TOK;
    aux[0] = 0.01f * ((float)E_NUM * lb) + 0.001f * z;
  }
}

// ---------------- gate+up GEMM (A contiguous from Xg), silu fused ----------------
__global__ __launch_bounds__(256) void gemm_gateup(
    const unsigned short* __restrict__ Xg, const unsigned short* __restrict__ gwt,
    const unsigned short* __restrict__ uwt,
    const int* __restrict__ cnt, const int* __restrict__ off,
    const float* __restrict__ slot_w, unsigned short* __restrict__ H)
{
  // XCD-chunk swizzle: 2048 tiles, 256 per expert -> expert e lives on XCD e
  int fid = blockIdx.x;
  int nid = (fid & 7)*(E_NUM*MT*NT_GU/8) + (fid >> 3);
  int e  = nid >> 8;          // 256 tiles per expert
  int r  = nid & 255;
  int n0 = (r >> 4) * BN;
  int mt = r & 15;
  int c = cnt[e*CSTRIDE];
  int row0 = mt*BM;
  if (row0 >= c) return;
  int rem = c - row0;
  int tid = threadIdx.x, wid = tid>>6, lane = tid&63;
  __shared__ unsigned short lds[BM*BK + 2*BN*BK];
  unsigned short* As = lds;
  unsigned short* Bg = lds + BM*BK;
  unsigned short* Bu = Bg + BN*BK;

  int sub = lane>>3;
  int skb = ((lane&7)<<4) ^ (sub<<4);
  const char* asrc[4];
  #pragma unroll
  for (int i=0;i<4;i++){
    int rr = (wid*4+i)*8 + sub;
    asrc[i] = (const char*)Xg + ((size_t)e*CAP + row0 + rr)*(D_DIM*2) + skb;
  }
  const char* bgsrc[2]; const char* busrc[2];
  #pragma unroll
  for (int i=0;i<2;i++){
    int rr = (wid*2+i)*8 + sub;
    size_t rowb = ((size_t)e*F_DIM + n0 + rr) * (D_DIM*2);
    bgsrc[i] = (const char*)gwt + rowb + skb;
    busrc[i] = (const char*)uwt + rowb + skb;
  }

  f32x4 accg[4][2] = {};
  f32x4 accu[4][2] = {};
  int wm = wid>>1, wn = wid&1;

  size_t koff = 0;
  for (int kt=0; kt<D_DIM/BK; ++kt, koff += BK*2){
    #pragma unroll
    for (int i=0;i<4;i++)
      gload16(asrc[i]+koff, (char*)As + (wid*4+i)*1024);
    #pragma unroll
    for (int i=0;i<2;i++){
      gload16(bgsrc[i]+koff, (char*)Bg + (wid*2+i)*1024);
      gload16(busrc[i]+koff, (char*)Bu + (wid*2+i)*1024);
    }
    __syncthreads();
    #pragma unroll
    for (int s=0;s<2;s++){
      int kc = s*4 + (lane>>4);
      bf16x8 a[4], bg[2], bu[2];
      #pragma unroll
      for (int m=0;m<4;m++){
        int ar = wm*64 + m*16 + (lane&15);
        a[m] = *(const bf16x8*)((const char*)As + ar*128 + ((kc<<4) ^ ((ar&7)<<4)));
      }
      #pragma unroll
      for (int n=0;n<2;n++){
        int br = wn*32 + n*16 + (lane&15);
        int bo = br*128 + ((kc<<4) ^ ((br&7)<<4));
        bg[n] = *(const bf16x8*)((const char*)Bg + bo);
        bu[n] = *(const bf16x8*)((const char*)Bu + bo);
      }
      #pragma unroll
      for (int m=0;m<4;m++){
        #pragma unroll
        for (int n=0;n<2;n++){
          accg[m][n] = __builtin_amdgcn_mfma_f32_16x16x32_bf16(a[m], bg[n], accg[m][n], 0,0,0);
          accu[m][n] = __builtin_amdgcn_mfma_f32_16x16x32_bf16(a[m], bu[n], accu[m][n], 0,0,0);
        }
      }
    }
    __syncthreads();
  }

  int offe = off[e];
  #pragma unroll
  for (int m=0;m<4;m++){
    #pragma unroll
    for (int j=0;j<4;j++){
      int row = wm*64 + m*16 + ((lane>>4)<<2) + j;
      if (row < rem){
        float wgt = slot_w[e*CAP + row0 + row];
        size_t hb = (size_t)(offe + row0 + row)*F_DIM;
        #pragma unroll
        for (int n=0;n<2;n++){
          int col = n0 + wn*32 + n*16 + (lane&15);
          float g = accg[m][n][j];
          float u = accu[m][n][j];
          float h = g * (1.f/(1.f+__expf(-g))) * u * wgt;
          H[hb + col] = f2bf(h);
        }
      }
    }
  }
}

// ---------------- down GEMM, atomic scatter into out ----------------
__global__ __launch_bounds__(256) void gemm_down(
    const unsigned short* __restrict__ H, const unsigned short* __restrict__ dwt,
    const int* __restrict__ cnt, const int* __restrict__ off,
    const int* __restrict__ slot_token, float* __restrict__ out)
{
  int fid = blockIdx.x;
  int nid = (fid & 7)*(E_NUM*MT*NT_DN/8) + (fid >> 3);
  int e  = nid >> 7;          // 128 tiles per expert
  int r  = nid & 127;
  int n0 = (r >> 4) * BN;
  int mt = r & 15;
  int c = cnt[e*CSTRIDE];
  int row0 = mt*BM;
  if (row0 >= c) return;
  int rem = c - row0;
  int tid = threadIdx.x, wid = tid>>6, lane = tid&63;
  __shared__ unsigned short lds[BM*BK + BN*BK];
  unsigned short* As = lds;
  unsigned short* Bs = lds + BM*BK;
  int sub = lane>>3;
  int skb = ((lane&7)<<4) ^ (sub<<4);
  int offe = off[e];
  const char* asrc[4];
  #pragma unroll
  for (int i=0;i<4;i++){
    int rr = (wid*4+i)*8 + sub;
    asrc[i] = (const char*)H + ((size_t)offe + row0 + rr)*(F_DIM*2) + skb;
  }
  const char* bsrc[2];
  #pragma unroll
  for (int i=0;i<2;i++){
    int rr = (wid*2+i)*8 + sub;
    bsrc[i] = (const char*)dwt + ((size_t)e*D_DIM + n0 + rr)*(F_DIM*2) + skb;
  }
  f32x4 acc[4][2] = {};
  int wm = wid>>1, wn = wid&1;
  size_t koff = 0;
  for (int kt=0; kt<F_DIM/BK; ++kt, koff += BK*2){
    #pragma unroll
    for (int i=0;i<4;i++) gload16(asrc[i]+koff, (char*)As + (wid*4+i)*1024);
    #pragma unroll
    for (int i=0;i<2;i++) gload16(bsrc[i]+koff, (char*)Bs + (wid*2+i)*1024);
    __syncthreads();
    #pragma unroll
    for (int s=0;s<2;s++){
      int kc = s*4 + (lane>>4);
      bf16x8 a[4], b[2];
      #pragma unroll
      for (int m=0;m<4;m++){
        int ar = wm*64 + m*16 + (lane&15);
        a[m] = *(const bf16x8*)((const char*)As + ar*128 + ((kc<<4) ^ ((ar&7)<<4)));
      }
      #pragma unroll
      for (int n=0;n<2;n++){
        int br = wn*32 + n*16 + (lane&15);
        b[n] = *(const bf16x8*)((const char*)Bs + br*128 + ((kc<<4) ^ ((br&7)<<4)));
      }
      #pragma unroll
      for (int m=0;m<4;m++){
        #pragma unroll
        for (int n=0;n<2;n++)
          acc[m][n] = __builtin_amdgcn_mfma_f32_16x16x32_bf16(a[m], b[n], acc[m][n], 0,0,0);
      }
    }
    __syncthreads();
  }
  #pragma unroll
  for (int m=0;m<4;m++){
    #pragma unroll
    for (int j=0;j<4;j++){
      int row = wm*64 + m*16 + ((lane>>4)<<2) + j;
      if (row < rem){
        int tok = slot_token[e*CAP + row0 + row];
        #pragma unroll
        for (int n=0;n<2;n++){
          int col = n0 + wn*32 + n*16 + (lane&15);
          atomicAdd(&out[(size_t)tok*D_DIM + col], acc[m][n][j]);
        }
      }
    }
  }
}

extern "C" void kernel_launch(void* const* d_in, const int* in_sizes, int n_in,
                              void* d_out, int out_size, void* d_ws, size_t ws_size,
                              hipStream_t stream){
  const float* x  = (const float*)d_in[0];
  const float* rw = (const float*)d_in[1];
  const float* gw = (const float*)d_in[2];
  const float* uw = (const float*)d_in[3];
  const float* dw = (const float*)d_in[4];
  float* out = (float*)d_out;

  char* w = (char*)d_ws;
  unsigned short* Xg  = (unsigned short*)w;  w += (size_t)E_NUM*CAP*D_DIM*2;           // 16 MB
  unsigned short* gwt = (unsigned short*)w;  w += (size_t)E_NUM*D_DIM*F_DIM*2;         // 8 MB
  unsigned short* uwt = (unsigned short*)w;  w += (size_t)E_NUM*D_DIM*F_DIM*2;         // 8 MB
  unsigned short* dwt = (unsigned short*)w;  w += (size_t)E_NUM*F_DIM*D_DIM*2;         // 8 MB
  unsigned short* H   = (unsigned short*)w;  w += (size_t)(T_TOK*2 + BM)*F_DIM*2;      // ~17 MB
  int*   slot_token = (int*)w;               w += (size_t)E_NUM*CAP*4;
  float* slot_w     = (float*)w;             w += (size_t)E_NUM*CAP*4;
  char* meta = w;
  int*   cnt  = (int*)w;       w += E_NUM*CSTRIDE*4;
  int*   off  = (int*)w;       w += 128;
  float* Psum = (float*)w;     w += E_NUM*CSTRIDE*4;
  float* zsum = (float*)w;     w += 128;
  size_t meta_bytes = (size_t)(w - meta);

  hipMemsetAsync(d_out, 0, (size_t)out_size*sizeof(float), stream);
  hipMemsetAsync(meta, 0, meta_bytes, stream);

  transpose_kernel<<<dim3(F_DIM/64, D_DIM/64, E_NUM), 256, 0, stream>>>(gw, gwt, D_DIM, F_DIM);
  transpose_kernel<<<dim3(F_DIM/64, D_DIM/64, E_NUM), 256, 0, stream>>>(uw, uwt, D_DIM, F_DIM);
  transpose_kernel<<<dim3(D_DIM/64, F_DIM/64, E_NUM), 256, 0, stream>>>(dw, dwt, F_DIM, D_DIM);
  router_kernel<<<T_TOK/RB_TOK, 256, 0, stream>>>(x, rw, Xg, cnt, slot_token, slot_w, Psum, zsum);
  finalize_kernel<<<1, 64, 0, stream>>>(cnt, Psum, zsum, off, out + (size_t)T_TOK*D_DIM);
  gemm_gateup<<<E_NUM*MT*NT_GU, 256, 0, stream>>>(Xg, gwt, uwt, cnt, off, slot_w, H);
  gemm_down<<<E_NUM*MT*NT_DN, 256, 0, stream>>>(H, dwt, cnt, off, slot_token, out);
}

// Round 5
// 197.031 us; speedup vs baseline: 2.0028x; 1.1238x over previous
//
#include <hip/hip_runtime.h>

#define T_TOK 4096
#define D_DIM 512
#define F_DIM 1024
#define E_NUM 8
#define CAP   2048
#define BM    128
#define BN    64
#define BK    64
#define MT    (CAP/BM)      // 16
#define NT_GU (F_DIM/BN)    // 16
#define NT_DN (D_DIM/BN)    // 8
#define RB_TOK 32
#define CSTRIDE 32
#define RTR_BLOCKS (T_TOK/RB_TOK)   // 128

#define GU_HALF (BM*BK*2 + 2*BN*BK*2)   // 32768 bytes per buffer
#define DN_HALF (BM*BK*2 + BN*BK*2)     // 24576 bytes per buffer

typedef __bf16 bf16x8 __attribute__((ext_vector_type(8)));
typedef float  f32x4  __attribute__((ext_vector_type(4)));

__device__ __forceinline__ unsigned short f2bf(float f){
  unsigned int u = __builtin_bit_cast(unsigned int, f);
  u += 0x7FFFu + ((u >> 16) & 1u);
  return (unsigned short)(u >> 16);
}

__device__ __forceinline__ void gload16(const void* g, void* l){
  __builtin_amdgcn_global_load_lds(
      (const __attribute__((address_space(1))) unsigned int*)g,
      (__attribute__((address_space(3))) unsigned int*)l, 16, 0, 0);
}

// ============ fused prep: router (blocks 0..127) + 3 transposes ============
__global__ __launch_bounds__(256) void prep_kernel(
    const float* __restrict__ x, const float* __restrict__ rw,
    const float* __restrict__ gw, const float* __restrict__ uw, const float* __restrict__ dw,
    unsigned short* __restrict__ Xg,
    unsigned short* __restrict__ gwt, unsigned short* __restrict__ uwt, unsigned short* __restrict__ dwt,
    int* __restrict__ cnt, int* __restrict__ slot_token, float* __restrict__ slot_w,
    float* __restrict__ Psum, float* __restrict__ zsum)
{
  __shared__ __align__(16) char smem[18432];
  int b = blockIdx.x;
  int tid = threadIdx.x;

  if (b >= RTR_BLOCKS){
    // ---- transpose dispatcher: [E][R][C] fp32 -> [E][C][R] bf16 ----
    int tb = b - RTR_BLOCKS;
    int seg = tb >> 10;           // 0:gw 1:uw 2:dw   (1024 blocks each)
    int r1023 = tb & 1023;
    int e = r1023 >> 7;           // 128 blocks per expert
    int rr = r1023 & 127;
    const float* in; unsigned short* outp; int R, C, nbx;
    if (seg == 0){ in = gw; outp = gwt; R = D_DIM; C = F_DIM; nbx = F_DIM/64; }
    else if (seg == 1){ in = uw; outp = uwt; R = D_DIM; C = F_DIM; nbx = F_DIM/64; }
    else { in = dw; outp = dwt; R = F_DIM; C = D_DIM; nbx = D_DIM/64; }
    int c0 = (rr % nbx)*64, r0 = (rr / nbx)*64;
    const float* src = in + (size_t)e*R*C;
    unsigned short* dst = outp + (size_t)e*R*C;
    unsigned short (*tile)[66] = (unsigned short(*)[66])smem;
    #pragma unroll
    for (int i=0;i<16;i++){
      int idx = i*256+tid; int rl = idx>>6, cl = idx&63;
      tile[cl][rl] = f2bf(src[(size_t)(r0+rl)*C + (c0+cl)]);
    }
    __syncthreads();
    #pragma unroll
    for (int i=0;i<16;i++){
      int idx = i*256+tid; int cl = idx>>6, rl = idx&63;
      dst[(size_t)(c0+cl)*R + (r0+rl)] = tile[cl][rl];
    }
    return;
  }

  // ---- router: logits + softmax + top2 + aux partials + bf16 scatter into Xg ----
  float* rws          = (float*)smem;                    // 16384 B
  float (*lp)[E_NUM]  = (float(*)[E_NUM])(smem+16384);   // 1024 B
  float* lw1          = (float*)(smem+17408);
  float* lw2          = (float*)(smem+17536);
  float* llse         = (float*)(smem+17664);
  int*   li1          = (int*)(smem+17792);
  int*   li2          = (int*)(smem+17920);
  int*   lsl1         = (int*)(smem+18048);
  int*   lsl2         = (int*)(smem+18176);

  int wid = tid>>6, lane = tid&63;
  for (int i = tid; i < E_NUM*D_DIM; i += 256) rws[i] = rw[i];
  __syncthreads();

  uint4 pk[8];
  #pragma unroll
  for (int i=0;i<8;i++){
    int widx = wid*8 + i;
    int t = b*RB_TOK + widx;
    const float* xr = x + (size_t)t*D_DIM + lane*8;
    float4 xa = *(const float4*)xr;
    float4 xc = *(const float4*)(xr+4);
    pk[i].x = (unsigned)f2bf(xa.x) | ((unsigned)f2bf(xa.y)<<16);
    pk[i].y = (unsigned)f2bf(xa.z) | ((unsigned)f2bf(xa.w)<<16);
    pk[i].z = (unsigned)f2bf(xc.x) | ((unsigned)f2bf(xc.y)<<16);
    pk[i].w = (unsigned)f2bf(xc.z) | ((unsigned)f2bf(xc.w)<<16);

    float logit[E_NUM];
    #pragma unroll
    for (int e=0;e<E_NUM;e++){
      const float* wr = rws + e*D_DIM + lane*8;
      float4 wa = *(const float4*)wr;
      float4 wb = *(const float4*)(wr+4);
      float s = xa.x*wa.x + xa.y*wa.y + xa.z*wa.z + xa.w*wa.w
              + xc.x*wb.x + xc.y*wb.y + xc.z*wb.z + xc.w*wb.w;
      #pragma unroll
      for (int m=1;m<64;m<<=1) s += __shfl_xor(s, m);
      logit[e] = s;
    }
    float mx = logit[0];
    #pragma unroll
    for (int e=1;e<E_NUM;e++) mx = fmaxf(mx, logit[e]);
    float p[E_NUM]; float s = 0.f;
    #pragma unroll
    for (int e=0;e<E_NUM;e++){ p[e] = __expf(logit[e]-mx); s += p[e]; }
    float inv = 1.f/s;
    #pragma unroll
    for (int e=0;e<E_NUM;e++) p[e] *= inv;
    float lse = mx + __logf(s);
    int i1 = 0;
    #pragma unroll
    for (int e=1;e<E_NUM;e++) if (logit[e] > logit[i1]) i1 = e;
    int i2 = (i1==0) ? 1 : 0;
    #pragma unroll
    for (int e=0;e<E_NUM;e++) if (e != i1 && logit[e] > logit[i2]) i2 = e;
    if (lane == 0){
      float v1 = p[i1], v2 = p[i2];
      float invw = 1.f/(v1+v2);
      li1[widx] = i1; li2[widx] = i2;
      lw1[widx] = v1*invw; lw2[widx] = v2*invw;
      llse[widx] = lse;
      #pragma unroll
      for (int e=0;e<E_NUM;e++) lp[widx][e] = p[e];
    }
  }
  __syncthreads();

  if (tid < E_NUM){
    int e = tid, c = 0;
    #pragma unroll 4
    for (int j=0;j<RB_TOK;j++) c += (li1[j]==e) + (li2[j]==e);
    int idx = atomicAdd(&cnt[e*CSTRIDE], c);
    int tbase = b*RB_TOK;
    for (int j=0;j<RB_TOK;j++){
      if (li1[j]==e){ slot_token[e*CAP+idx] = tbase+j; slot_w[e*CAP+idx] = lw1[j]; lsl1[j] = e*CAP+idx; idx++; }
      if (li2[j]==e){ slot_token[e*CAP+idx] = tbase+j; slot_w[e*CAP+idx] = lw2[j]; lsl2[j] = e*CAP+idx; idx++; }
    }
    float ps = 0.f;
    #pragma unroll 4
    for (int j=0;j<RB_TOK;j++) ps += lp[j][e];
    atomicAdd(&Psum[e*CSTRIDE], ps);
  } else if (tid == 64){
    float zs = 0.f;
    #pragma unroll 4
    for (int j=0;j<RB_TOK;j++){ float l = llse[j]; zs += l*l; }
    atomicAdd(zsum, zs);
  }
  __syncthreads();

  #pragma unroll
  for (int i=0;i<8;i++){
    int widx = wid*8 + i;
    int s1 = lsl1[widx], s2 = lsl2[widx];
    *(uint4*)((char*)Xg + (size_t)s1*(D_DIM*2) + lane*16) = pk[i];
    *(uint4*)((char*)Xg + (size_t)s2*(D_DIM*2) + lane*16) = pk[i];
  }
}

// ---------------- prefix offsets + aux loss ----------------
__global__ void finalize_kernel(const int* __restrict__ cnt, const float* __restrict__ Psum,
                                const float* __restrict__ zsum, int* __restrict__ off,
                                float* __restrict__ aux){
  if (threadIdx.x == 0 && blockIdx.x == 0){
    int o = 0; float lb = 0.f;
    #pragma unroll
    for (int e=0;e<E_NUM;e++){
      off[e] = o; o += cnt[e*CSTRIDE];
      float f = (float)cnt[e*CSTRIDE] / (float)(T_TOK*2);
      float P = Psum[e*CSTRIDE] / (float)T_TOK;
      lb += f*P;
    }
    float z = zsum[0] / (float)T_TOK;
    aux[0] = 0.01f * ((float)E_NUM * lb) + 0.001f * z;
  }
}

// ---------------- gate+up GEMM: double-buffered LDS, deferred drain ----------------
__global__ __launch_bounds__(256) void gemm_gateup(
    const unsigned short* __restrict__ Xg, const unsigned short* __restrict__ gwt,
    const unsigned short* __restrict__ uwt,
    const int* __restrict__ cnt, const int* __restrict__ off,
    const float* __restrict__ slot_w, unsigned short* __restrict__ H)
{
  int fid = blockIdx.x;
  int nid = (fid & 7)*(E_NUM*MT*NT_GU/8) + (fid >> 3);
  int e  = nid >> 8;
  int r  = nid & 255;
  int n0 = (r >> 4) * BN;
  int mt = r & 15;
  int c = cnt[e*CSTRIDE];
  int row0 = mt*BM;
  if (row0 >= c) return;
  int rem = c - row0;
  int tid = threadIdx.x, wid = tid>>6, lane = tid&63;
  __shared__ __align__(16) char arena[2*GU_HALF];

  int sub = lane>>3;
  int skb = ((lane&7)<<4) ^ (sub<<4);
  const char* asrc[4];
  #pragma unroll
  for (int i=0;i<4;i++){
    int rr = (wid*4+i)*8 + sub;
    asrc[i] = (const char*)Xg + ((size_t)e*CAP + row0 + rr)*(D_DIM*2) + skb;
  }
  const char* bgsrc[2]; const char* busrc[2];
  #pragma unroll
  for (int i=0;i<2;i++){
    int rr = (wid*2+i)*8 + sub;
    size_t rowb = ((size_t)e*F_DIM + n0 + rr) * (D_DIM*2);
    bgsrc[i] = (const char*)gwt + rowb + skb;
    busrc[i] = (const char*)uwt + rowb + skb;
  }

  f32x4 accg[4][2] = {};
  f32x4 accu[4][2] = {};
  int wm = wid>>1, wn = wid&1;

  auto STAGE = [&](int buf, int kt){
    size_t ko = (size_t)kt*BK*2;
    char* base = arena + buf*GU_HALF;
    #pragma unroll
    for (int i=0;i<4;i++)
      gload16(asrc[i]+ko, base + (wid*4+i)*1024);
    #pragma unroll
    for (int i=0;i<2;i++){
      gload16(bgsrc[i]+ko, base + BM*BK*2 + (wid*2+i)*1024);
      gload16(busrc[i]+ko, base + BM*BK*2 + BN*BK*2 + (wid*2+i)*1024);
    }
  };
  auto COMPUTE = [&](int buf){
    const char* base = arena + buf*GU_HALF;
    const char* As = base;
    const char* Bg = base + BM*BK*2;
    const char* Bu = base + BM*BK*2 + BN*BK*2;
    #pragma unroll
    for (int s=0;s<2;s++){
      int kc = s*4 + (lane>>4);
      bf16x8 a[4], bg[2], bu[2];
      #pragma unroll
      for (int m=0;m<4;m++){
        int ar = wm*64 + m*16 + (lane&15);
        a[m] = *(const bf16x8*)(As + ar*128 + ((kc<<4) ^ ((ar&7)<<4)));
      }
      #pragma unroll
      for (int n=0;n<2;n++){
        int br = wn*32 + n*16 + (lane&15);
        int bo = br*128 + ((kc<<4) ^ ((br&7)<<4));
        bg[n] = *(const bf16x8*)(Bg + bo);
        bu[n] = *(const bf16x8*)(Bu + bo);
      }
      #pragma unroll
      for (int m=0;m<4;m++){
        #pragma unroll
        for (int n=0;n<2;n++){
          accg[m][n] = __builtin_amdgcn_mfma_f32_16x16x32_bf16(a[m], bg[n], accg[m][n], 0,0,0);
          accu[m][n] = __builtin_amdgcn_mfma_f32_16x16x32_bf16(a[m], bu[n], accu[m][n], 0,0,0);
        }
      }
    }
  };

  STAGE(0, 0);
  __syncthreads();
  int cur = 0;
  for (int kt=0; kt<D_DIM/BK-1; ++kt){
    STAGE(cur^1, kt+1);     // next tile flies under this tile's MFMAs
    COMPUTE(cur);
    __syncthreads();
    cur ^= 1;
  }
  COMPUTE(cur);

  int offe = off[e];
  #pragma unroll
  for (int m=0;m<4;m++){
    #pragma unroll
    for (int j=0;j<4;j++){
      int row = wm*64 + m*16 + ((lane>>4)<<2) + j;
      if (row < rem){
        float wgt = slot_w[e*CAP + row0 + row];
        size_t hb = (size_t)(offe + row0 + row)*F_DIM;
        #pragma unroll
        for (int n=0;n<2;n++){
          int col = n0 + wn*32 + n*16 + (lane&15);
          float g = accg[m][n][j];
          float u = accu[m][n][j];
          float h = g * (1.f/(1.f+__expf(-g))) * u * wgt;
          H[hb + col] = f2bf(h);
        }
      }
    }
  }
}

// ---------------- down GEMM: double-buffered, atomic scatter into out ----------------
__global__ __launch_bounds__(256) void gemm_down(
    const unsigned short* __restrict__ H, const unsigned short* __restrict__ dwt,
    const int* __restrict__ cnt, const int* __restrict__ off,
    const int* __restrict__ slot_token, float* __restrict__ out)
{
  int fid = blockIdx.x;
  int nid = (fid & 7)*(E_NUM*MT*NT_DN/8) + (fid >> 3);
  int e  = nid >> 7;
  int r  = nid & 127;
  int n0 = (r >> 4) * BN;
  int mt = r & 15;
  int c = cnt[e*CSTRIDE];
  int row0 = mt*BM;
  if (row0 >= c) return;
  int rem = c - row0;
  int tid = threadIdx.x, wid = tid>>6, lane = tid&63;
  __shared__ __align__(16) char arena[2*DN_HALF];
  int sub = lane>>3;
  int skb = ((lane&7)<<4) ^ (sub<<4);
  int offe = off[e];
  const char* asrc[4];
  #pragma unroll
  for (int i=0;i<4;i++){
    int rr = (wid*4+i)*8 + sub;
    asrc[i] = (const char*)H + ((size_t)offe + row0 + rr)*(F_DIM*2) + skb;
  }
  const char* bsrc[2];
  #pragma unroll
  for (int i=0;i<2;i++){
    int rr = (wid*2+i)*8 + sub;
    bsrc[i] = (const char*)dwt + ((size_t)e*D_DIM + n0 + rr)*(F_DIM*2) + skb;
  }
  f32x4 acc[4][2] = {};
  int wm = wid>>1, wn = wid&1;

  auto STAGE = [&](int buf, int kt){
    size_t ko = (size_t)kt*BK*2;
    char* base = arena + buf*DN_HALF;
    #pragma unroll
    for (int i=0;i<4;i++) gload16(asrc[i]+ko, base + (wid*4+i)*1024);
    #pragma unroll
    for (int i=0;i<2;i++) gload16(bsrc[i]+ko, base + BM*BK*2 + (wid*2+i)*1024);
  };
  auto COMPUTE = [&](int buf){
    const char* base = arena + buf*DN_HALF;
    const char* As = base;
    const char* Bs = base + BM*BK*2;
    #pragma unroll
    for (int s=0;s<2;s++){
      int kc = s*4 + (lane>>4);
      bf16x8 a[4], bb[2];
      #pragma unroll
      for (int m=0;m<4;m++){
        int ar = wm*64 + m*16 + (lane&15);
        a[m] = *(const bf16x8*)(As + ar*128 + ((kc<<4) ^ ((ar&7)<<4)));
      }
      #pragma unroll
      for (int n=0;n<2;n++){
        int br = wn*32 + n*16 + (lane&15);
        bb[n] = *(const bf16x8*)(Bs + br*128 + ((kc<<4) ^ ((br&7)<<4)));
      }
      #pragma unroll
      for (int m=0;m<4;m++){
        #pragma unroll
        for (int n=0;n<2;n++)
          acc[m][n] = __builtin_amdgcn_mfma_f32_16x16x32_bf16(a[m], bb[n], acc[m][n], 0,0,0);
      }
    }
  };

  STAGE(0, 0);
  __syncthreads();
  int cur = 0;
  for (int kt=0; kt<F_DIM/BK-1; ++kt){
    STAGE(cur^1, kt+1);
    COMPUTE(cur);
    __syncthreads();
    cur ^= 1;
  }
  COMPUTE(cur);

  #pragma unroll
  for (int m=0;m<4;m++){
    #pragma unroll
    for (int j=0;j<4;j++){
      int row = wm*64 + m*16 + ((lane>>4)<<2) + j;
      if (row < rem){
        int tok = slot_token[e*CAP + row0 + row];
        #pragma unroll
        for (int n=0;n<2;n++){
          int col = n0 + wn*32 + n*16 + (lane&15);
          atomicAdd(&out[(size_t)tok*D_DIM + col], acc[m][n][j]);
        }
      }
    }
  }
}

extern "C" void kernel_launch(void* const* d_in, const int* in_sizes, int n_in,
                              void* d_out, int out_size, void* d_ws, size_t ws_size,
                              hipStream_t stream){
  const float* x  = (const float*)d_in[0];
  const float* rw = (const float*)d_in[1];
  const float* gw = (const float*)d_in[2];
  const float* uw = (const float*)d_in[3];
  const float* dw = (const float*)d_in[4];
  float* out = (float*)d_out;

  char* w = (char*)d_ws;
  unsigned short* Xg  = (unsigned short*)w;  w += (size_t)E_NUM*CAP*D_DIM*2;
  unsigned short* gwt = (unsigned short*)w;  w += (size_t)E_NUM*D_DIM*F_DIM*2;
  unsigned short* uwt = (unsigned short*)w;  w += (size_t)E_NUM*D_DIM*F_DIM*2;
  unsigned short* dwt = (unsigned short*)w;  w += (size_t)E_NUM*F_DIM*D_DIM*2;
  unsigned short* H   = (unsigned short*)w;  w += (size_t)(T_TOK*2 + BM)*F_DIM*2;
  int*   slot_token = (int*)w;               w += (size_t)E_NUM*CAP*4;
  float* slot_w     = (float*)w;             w += (size_t)E_NUM*CAP*4;
  char* meta = w;
  int*   cnt  = (int*)w;       w += E_NUM*CSTRIDE*4;
  int*   off  = (int*)w;       w += 128;
  float* Psum = (float*)w;     w += E_NUM*CSTRIDE*4;
  float* zsum = (float*)w;     w += 128;
  size_t meta_bytes = (size_t)(w - meta);

  (void)hipMemsetAsync(d_out, 0, (size_t)out_size*sizeof(float), stream);
  (void)hipMemsetAsync(meta, 0, meta_bytes, stream);

  prep_kernel<<<RTR_BLOCKS + 3*1024, 256, 0, stream>>>(
      x, rw, gw, uw, dw, Xg, gwt, uwt, dwt, cnt, slot_token, slot_w, Psum, zsum);
  finalize_kernel<<<1, 64, 0, stream>>>(cnt, Psum, zsum, off, out + (size_t)T_TOK*D_DIM);
  gemm_gateup<<<E_NUM*MT*NT_GU, 256, 0, stream>>>(Xg, gwt, uwt, cnt, off, slot_w, H);
  gemm_down<<<E_NUM*MT*NT_DN, 256, 0, stream>>>(H, dwt, cnt, off, slot_token, out);
}

// Round 7
// 193.565 us; speedup vs baseline: 2.0386x; 1.0179x over previous
//
#include <hip/hip_runtime.h>

#define T_TOK 4096
#define D_DIM 512
#define F_DIM 1024
#define E_NUM 8
#define CAP   2048
#define BM    128
#define BN    64
#define BK    64
#define MT    (CAP/BM)      // 16
#define NT_GU (F_DIM/BN)    // 16
#define NT_DN (D_DIM/BN)    // 8
#define RB_TOK 32
#define CSTRIDE 32
#define RTR_BLOCKS (T_TOK/RB_TOK)   // 128

#define GU_HALF (BM*BK*2 + 2*BN*BK*2)   // 32768 bytes per buffer
#define DN_HALF (BM*BK*2 + BN*BK*2)     // 24576 bytes per buffer

typedef __bf16 bf16x8 __attribute__((ext_vector_type(8)));
typedef float  f32x4  __attribute__((ext_vector_type(4)));

__device__ __forceinline__ unsigned short f2bf(float f){
  unsigned int u = __builtin_bit_cast(unsigned int, f);
  u += 0x7FFFu + ((u >> 16) & 1u);
  return (unsigned short)(u >> 16);
}

__device__ __forceinline__ void gload16(const void* g, void* l){
  __builtin_amdgcn_global_load_lds(
      (const __attribute__((address_space(1))) unsigned int*)g,
      (__attribute__((address_space(3))) unsigned int*)l, 16, 0, 0);
}

// ============ fused prep: router (blocks 0..127) + 3 transposes ============
__global__ __launch_bounds__(256) void prep_kernel(
    const float* __restrict__ x, const float* __restrict__ rw,
    const float* __restrict__ gw, const float* __restrict__ uw, const float* __restrict__ dw,
    unsigned short* __restrict__ Xg,
    unsigned short* __restrict__ gwt, unsigned short* __restrict__ uwt, unsigned short* __restrict__ dwt,
    int* __restrict__ cnt, int* __restrict__ slot_token, float* __restrict__ slot_w,
    float* __restrict__ Psum, float* __restrict__ zsum)
{
  __shared__ __align__(16) char smem[18432];
  int b = blockIdx.x;
  int tid = threadIdx.x;

  if (b >= RTR_BLOCKS){
    // ---- transpose: [E][R][C] fp32 -> [E][C][R] bf16, vectorized both sides ----
    int tb = b - RTR_BLOCKS;
    int seg = tb >> 10;           // 0:gw 1:uw 2:dw   (1024 blocks each)
    int r1023 = tb & 1023;
    int e = r1023 >> 7;           // 128 blocks per expert
    int rr = r1023 & 127;
    const float* in; unsigned short* outp; int R, C, nbx;
    if (seg == 0){ in = gw; outp = gwt; R = D_DIM; C = F_DIM; nbx = F_DIM/64; }
    else if (seg == 1){ in = uw; outp = uwt; R = D_DIM; C = F_DIM; nbx = F_DIM/64; }
    else { in = dw; outp = dwt; R = F_DIM; C = D_DIM; nbx = D_DIM/64; }
    int c0 = (rr % nbx)*64, r0 = (rr / nbx)*64;
    const float* src = in + (size_t)e*R*C;
    unsigned short* dst = outp + (size_t)e*R*C;
    unsigned short* tile = (unsigned short*)smem;   // [64][68] shorts

    // read: float4 per lane (coalesced), 4 scalar bf16 scatters to LDS
    #pragma unroll
    for (int i=0;i<4;i++){
      int idx = i*256+tid;
      int rl = idx >> 4;          // 0..63
      int cseg = idx & 15;        // 0..15
      float4 v = *(const float4*)(src + (size_t)(r0+rl)*C + c0 + cseg*4);
      tile[(cseg*4+0)*68 + rl] = f2bf(v.x);
      tile[(cseg*4+1)*68 + rl] = f2bf(v.y);
      tile[(cseg*4+2)*68 + rl] = f2bf(v.z);
      tile[(cseg*4+3)*68 + rl] = f2bf(v.w);
    }
    __syncthreads();
    // write: 8 bf16 per lane -> uint4 global store (coalesced 16B/lane)
    #pragma unroll
    for (int i=0;i<2;i++){
      int idx = i*256+tid;
      int c = idx >> 3;           // 0..63
      int rseg = idx & 7;         // 0..7
      ushort4 a = *(ushort4*)&tile[c*68 + rseg*8];
      ushort4 bq = *(ushort4*)&tile[c*68 + rseg*8 + 4];
      uint4 o;
      o.x = (unsigned)a.x  | ((unsigned)a.y<<16);
      o.y = (unsigned)a.z  | ((unsigned)a.w<<16);
      o.z = (unsigned)bq.x | ((unsigned)bq.y<<16);
      o.w = (unsigned)bq.z | ((unsigned)bq.w<<16);
      *(uint4*)(dst + (size_t)(c0+c)*R + r0 + rseg*8) = o;
    }
    return;
  }

  // ---- router: logits + softmax + top2 + aux partials + bf16 scatter into Xg ----
  float* rws          = (float*)smem;                    // 16384 B
  float (*lp)[E_NUM]  = (float(*)[E_NUM])(smem+16384);   // 1024 B
  float* lw1          = (float*)(smem+17408);
  float* lw2          = (float*)(smem+17536);
  float* llse         = (float*)(smem+17664);
  int*   li1          = (int*)(smem+17792);
  int*   li2          = (int*)(smem+17920);
  int*   lsl1         = (int*)(smem+18048);
  int*   lsl2         = (int*)(smem+18176);

  int wid = tid>>6, lane = tid&63;
  for (int i = tid; i < E_NUM*D_DIM; i += 256) rws[i] = rw[i];
  __syncthreads();

  uint4 pk[8];
  #pragma unroll
  for (int i=0;i<8;i++){
    int widx = wid*8 + i;
    int t = b*RB_TOK + widx;
    const float* xr = x + (size_t)t*D_DIM + lane*8;
    float4 xa = *(const float4*)xr;
    float4 xc = *(const float4*)(xr+4);
    pk[i].x = (unsigned)f2bf(xa.x) | ((unsigned)f2bf(xa.y)<<16);
    pk[i].y = (unsigned)f2bf(xa.z) | ((unsigned)f2bf(xa.w)<<16);
    pk[i].z = (unsigned)f2bf(xc.x) | ((unsigned)f2bf(xc.y)<<16);
    pk[i].w = (unsigned)f2bf(xc.z) | ((unsigned)f2bf(xc.w)<<16);

    float logit[E_NUM];
    #pragma unroll
    for (int e=0;e<E_NUM;e++){
      const float* wr = rws + e*D_DIM + lane*8;
      float4 wa = *(const float4*)wr;
      float4 wb = *(const float4*)(wr+4);
      float s = xa.x*wa.x + xa.y*wa.y + xa.z*wa.z + xa.w*wa.w
              + xc.x*wb.x + xc.y*wb.y + xc.z*wb.z + xc.w*wb.w;
      #pragma unroll
      for (int m=1;m<64;m<<=1) s += __shfl_xor(s, m);
      logit[e] = s;
    }
    float mx = logit[0];
    #pragma unroll
    for (int e=1;e<E_NUM;e++) mx = fmaxf(mx, logit[e]);
    float p[E_NUM]; float s = 0.f;
    #pragma unroll
    for (int e=0;e<E_NUM;e++){ p[e] = __expf(logit[e]-mx); s += p[e]; }
    float inv = 1.f/s;
    #pragma unroll
    for (int e=0;e<E_NUM;e++) p[e] *= inv;
    float lse = mx + __logf(s);
    int i1 = 0;
    #pragma unroll
    for (int e=1;e<E_NUM;e++) if (logit[e] > logit[i1]) i1 = e;
    int i2 = (i1==0) ? 1 : 0;
    #pragma unroll
    for (int e=0;e<E_NUM;e++) if (e != i1 && logit[e] > logit[i2]) i2 = e;
    if (lane == 0){
      float v1 = p[i1], v2 = p[i2];
      float invw = 1.f/(v1+v2);
      li1[widx] = i1; li2[widx] = i2;
      lw1[widx] = v1*invw; lw2[widx] = v2*invw;
      llse[widx] = lse;
      #pragma unroll
      for (int e=0;e<E_NUM;e++) lp[widx][e] = p[e];
    }
  }
  __syncthreads();

  if (tid < E_NUM){
    int e = tid, c = 0;
    #pragma unroll 4
    for (int j=0;j<RB_TOK;j++) c += (li1[j]==e) + (li2[j]==e);
    int idx = atomicAdd(&cnt[e*CSTRIDE], c);
    int tbase = b*RB_TOK;
    for (int j=0;j<RB_TOK;j++){
      if (li1[j]==e){ slot_token[e*CAP+idx] = tbase+j; slot_w[e*CAP+idx] = lw1[j]; lsl1[j] = e*CAP+idx; idx++; }
      if (li2[j]==e){ slot_token[e*CAP+idx] = tbase+j; slot_w[e*CAP+idx] = lw2[j]; lsl2[j] = e*CAP+idx; idx++; }
    }
    float ps = 0.f;
    #pragma unroll 4
    for (int j=0;j<RB_TOK;j++) ps += lp[j][e];
    atomicAdd(&Psum[e*CSTRIDE], ps);
  } else if (tid == 64){
    float zs = 0.f;
    #pragma unroll 4
    for (int j=0;j<RB_TOK;j++){ float l = llse[j]; zs += l*l; }
    atomicAdd(zsum, zs);
  }
  __syncthreads();

  #pragma unroll
  for (int i=0;i<8;i++){
    int widx = wid*8 + i;
    int s1 = lsl1[widx], s2 = lsl2[widx];
    *(uint4*)((char*)Xg + (size_t)s1*(D_DIM*2) + lane*16) = pk[i];
    *(uint4*)((char*)Xg + (size_t)s2*(D_DIM*2) + lane*16) = pk[i];
  }
}

// ---------------- gate+up GEMM: double-buffered LDS, deferred drain ----------------
__global__ __launch_bounds__(256) void gemm_gateup(
    const unsigned short* __restrict__ Xg, const unsigned short* __restrict__ gwt,
    const unsigned short* __restrict__ uwt,
    const int* __restrict__ cnt,
    const float* __restrict__ slot_w, unsigned short* __restrict__ H)
{
  int fid = blockIdx.x;
  int nid = (fid & 7)*(E_NUM*MT*NT_GU/8) + (fid >> 3);
  int e  = nid >> 8;
  int r  = nid & 255;
  int n0 = (r >> 4) * BN;
  int mt = r & 15;
  int c = cnt[e*CSTRIDE];
  int row0 = mt*BM;
  if (row0 >= c) return;
  int rem = c - row0;
  int offe = 0;
  #pragma unroll
  for (int i=0;i<E_NUM;i++) offe += (i < e) ? cnt[i*CSTRIDE] : 0;
  int tid = threadIdx.x, wid = tid>>6, lane = tid&63;
  __shared__ __align__(16) char arena[2*GU_HALF];

  int sub = lane>>3;
  int skb = ((lane&7)<<4) ^ (sub<<4);
  const char* asrc[4];
  #pragma unroll
  for (int i=0;i<4;i++){
    int rr = (wid*4+i)*8 + sub;
    asrc[i] = (const char*)Xg + ((size_t)e*CAP + row0 + rr)*(D_DIM*2) + skb;
  }
  const char* bgsrc[2]; const char* busrc[2];
  #pragma unroll
  for (int i=0;i<2;i++){
    int rr = (wid*2+i)*8 + sub;
    size_t rowb = ((size_t)e*F_DIM + n0 + rr) * (D_DIM*2);
    bgsrc[i] = (const char*)gwt + rowb + skb;
    busrc[i] = (const char*)uwt + rowb + skb;
  }

  f32x4 accg[4][2] = {};
  f32x4 accu[4][2] = {};
  int wm = wid>>1, wn = wid&1;

  auto STAGE = [&](int buf, int kt){
    size_t ko = (size_t)kt*BK*2;
    char* base = arena + buf*GU_HALF;
    #pragma unroll
    for (int i=0;i<4;i++)
      gload16(asrc[i]+ko, base + (wid*4+i)*1024);
    #pragma unroll
    for (int i=0;i<2;i++){
      gload16(bgsrc[i]+ko, base + BM*BK*2 + (wid*2+i)*1024);
      gload16(busrc[i]+ko, base + BM*BK*2 + BN*BK*2 + (wid*2+i)*1024);
    }
  };
  auto COMPUTE = [&](int buf){
    const char* base = arena + buf*GU_HALF;
    const char* As = base;
    const char* Bg = base + BM*BK*2;
    const char* Bu = base + BM*BK*2 + BN*BK*2;
    #pragma unroll
    for (int s=0;s<2;s++){
      int kc = s*4 + (lane>>4);
      bf16x8 a[4], bg[2], bu[2];
      #pragma unroll
      for (int m=0;m<4;m++){
        int ar = wm*64 + m*16 + (lane&15);
        a[m] = *(const bf16x8*)(As + ar*128 + ((kc<<4) ^ ((ar&7)<<4)));
      }
      #pragma unroll
      for (int n=0;n<2;n++){
        int br = wn*32 + n*16 + (lane&15);
        int bo = br*128 + ((kc<<4) ^ ((br&7)<<4));
        bg[n] = *(const bf16x8*)(Bg + bo);
        bu[n] = *(const bf16x8*)(Bu + bo);
      }
      #pragma unroll
      for (int m=0;m<4;m++){
        #pragma unroll
        for (int n=0;n<2;n++){
          accg[m][n] = __builtin_amdgcn_mfma_f32_16x16x32_bf16(a[m], bg[n], accg[m][n], 0,0,0);
          accu[m][n] = __builtin_amdgcn_mfma_f32_16x16x32_bf16(a[m], bu[n], accu[m][n], 0,0,0);
        }
      }
    }
  };

  STAGE(0, 0);
  __syncthreads();
  int cur = 0;
  for (int kt=0; kt<D_DIM/BK-1; ++kt){
    STAGE(cur^1, kt+1);
    COMPUTE(cur);
    __syncthreads();
    cur ^= 1;
  }
  COMPUTE(cur);

  #pragma unroll
  for (int m=0;m<4;m++){
    #pragma unroll
    for (int j=0;j<4;j++){
      int row = wm*64 + m*16 + ((lane>>4)<<2) + j;
      if (row < rem){
        float wgt = slot_w[e*CAP + row0 + row];
        size_t hb = (size_t)(offe + row0 + row)*F_DIM;
        #pragma unroll
        for (int n=0;n<2;n++){
          int col = n0 + wn*32 + n*16 + (lane&15);
          float g = accg[m][n][j];
          float u = accu[m][n][j];
          float h = g * (1.f/(1.f+__expf(-g))) * u * wgt;
          H[hb + col] = f2bf(h);
        }
      }
    }
  }
}

// ---------------- down GEMM: double-buffered, atomic scatter into out; aux in block 0 ----------------
__global__ __launch_bounds__(256) void gemm_down(
    const unsigned short* __restrict__ H, const unsigned short* __restrict__ dwt,
    const int* __restrict__ cnt,
    const int* __restrict__ slot_token, float* __restrict__ out,
    const float* __restrict__ Psum, const float* __restrict__ zsum)
{
  int fid = blockIdx.x;
  int tid = threadIdx.x;
  if (fid == 0 && tid == 0){
    float lb = 0.f;
    #pragma unroll
    for (int e=0;e<E_NUM;e++){
      float f = (float)cnt[e*CSTRIDE] / (float)(T_TOK*2);
      float P = Psum[e*CSTRIDE] / (float)T_TOK;
      lb += f*P;
    }
    float z = zsum[0] / (float)T_TOK;
    out[(size_t)T_TOK*D_DIM] = 0.01f * ((float)E_NUM * lb) + 0.001f * z;
  }
  int nid = (fid & 7)*(E_NUM*MT*NT_DN/8) + (fid >> 3);
  int e  = nid >> 7;
  int r  = nid & 127;
  int n0 = (r >> 4) * BN;
  int mt = r & 15;
  int c = cnt[e*CSTRIDE];
  int row0 = mt*BM;
  if (row0 >= c) return;
  int rem = c - row0;
  int offe = 0;
  #pragma unroll
  for (int i=0;i<E_NUM;i++) offe += (i < e) ? cnt[i*CSTRIDE] : 0;
  int wid = tid>>6, lane = tid&63;
  __shared__ __align__(16) char arena[2*DN_HALF];
  int sub = lane>>3;
  int skb = ((lane&7)<<4) ^ (sub<<4);
  const char* asrc[4];
  #pragma unroll
  for (int i=0;i<4;i++){
    int rr = (wid*4+i)*8 + sub;
    asrc[i] = (const char*)H + ((size_t)offe + row0 + rr)*(F_DIM*2) + skb;
  }
  const char* bsrc[2];
  #pragma unroll
  for (int i=0;i<2;i++){
    int rr = (wid*2+i)*8 + sub;
    bsrc[i] = (const char*)dwt + ((size_t)e*D_DIM + n0 + rr)*(F_DIM*2) + skb;
  }
  f32x4 acc[4][2] = {};
  int wm = wid>>1, wn = wid&1;

  auto STAGE = [&](int buf, int kt){
    size_t ko = (size_t)kt*BK*2;
    char* base = arena + buf*DN_HALF;
    #pragma unroll
    for (int i=0;i<4;i++) gload16(asrc[i]+ko, base + (wid*4+i)*1024);
    #pragma unroll
    for (int i=0;i<2;i++) gload16(bsrc[i]+ko, base + BM*BK*2 + (wid*2+i)*1024);
  };
  auto COMPUTE = [&](int buf){
    const char* base = arena + buf*DN_HALF;
    const char* As = base;
    const char* Bs = base + BM*BK*2;
    #pragma unroll
    for (int s=0;s<2;s++){
      int kc = s*4 + (lane>>4);
      bf16x8 a[4], bb[2];
      #pragma unroll
      for (int m=0;m<4;m++){
        int ar = wm*64 + m*16 + (lane&15);
        a[m] = *(const bf16x8*)(As + ar*128 + ((kc<<4) ^ ((ar&7)<<4)));
      }
      #pragma unroll
      for (int n=0;n<2;n++){
        int br = wn*32 + n*16 + (lane&15);
        bb[n] = *(const bf16x8*)(Bs + br*128 + ((kc<<4) ^ ((br&7)<<4)));
      }
      #pragma unroll
      for (int m=0;m<4;m++){
        #pragma unroll
        for (int n=0;n<2;n++)
          acc[m][n] = __builtin_amdgcn_mfma_f32_16x16x32_bf16(a[m], bb[n], acc[m][n], 0,0,0);
      }
    }
  };

  STAGE(0, 0);
  __syncthreads();
  int cur = 0;
  for (int kt=0; kt<F_DIM/BK-1; ++kt){
    STAGE(cur^1, kt+1);
    COMPUTE(cur);
    __syncthreads();
    cur ^= 1;
  }
  COMPUTE(cur);

  #pragma unroll
  for (int m=0;m<4;m++){
    #pragma unroll
    for (int j=0;j<4;j++){
      int row = wm*64 + m*16 + ((lane>>4)<<2) + j;
      if (row < rem){
        int tok = slot_token[e*CAP + row0 + row];
        #pragma unroll
        for (int n=0;n<2;n++){
          int col = n0 + wn*32 + n*16 + (lane&15);
          atomicAdd(&out[(size_t)tok*D_DIM + col], acc[m][n][j]);
        }
      }
    }
  }
}

extern "C" void kernel_launch(void* const* d_in, const int* in_sizes, int n_in,
                              void* d_out, int out_size, void* d_ws, size_t ws_size,
                              hipStream_t stream){
  const float* x  = (const float*)d_in[0];
  const float* rw = (const float*)d_in[1];
  const float* gw = (const float*)d_in[2];
  const float* uw = (const float*)d_in[3];
  const float* dw = (const float*)d_in[4];
  float* out = (float*)d_out;

  char* w = (char*)d_ws;
  unsigned short* Xg  = (unsigned short*)w;  w += (size_t)E_NUM*CAP*D_DIM*2;
  unsigned short* gwt = (unsigned short*)w;  w += (size_t)E_NUM*D_DIM*F_DIM*2;
  unsigned short* uwt = (unsigned short*)w;  w += (size_t)E_NUM*D_DIM*F_DIM*2;
  unsigned short* dwt = (unsigned short*)w;  w += (size_t)E_NUM*F_DIM*D_DIM*2;
  unsigned short* H   = (unsigned short*)w;  w += (size_t)(T_TOK*2 + BM)*F_DIM*2;
  int*   slot_token = (int*)w;               w += (size_t)E_NUM*CAP*4;
  float* slot_w     = (float*)w;             w += (size_t)E_NUM*CAP*4;
  char* meta = w;
  int*   cnt  = (int*)w;       w += E_NUM*CSTRIDE*4;
  float* Psum = (float*)w;     w += E_NUM*CSTRIDE*4;
  float* zsum = (float*)w;     w += 128;
  size_t meta_bytes = (size_t)(w - meta);

  (void)hipMemsetAsync(d_out, 0, (size_t)out_size*sizeof(float), stream);
  (void)hipMemsetAsync(meta, 0, meta_bytes, stream);

  prep_kernel<<<RTR_BLOCKS + 3*1024, 256, 0, stream>>>(
      x, rw, gw, uw, dw, Xg, gwt, uwt, dwt, cnt, slot_token, slot_w, Psum, zsum);
  gemm_gateup<<<E_NUM*MT*NT_GU, 256, 0, stream>>>(Xg, gwt, uwt, cnt, slot_w, H);
  gemm_down<<<E_NUM*MT*NT_DN, 256, 0, stream>>>(H, dwt, cnt, slot_token, out, Psum, zsum);
}